// Round 6
// baseline (183.630 us; speedup 1.0000x reference)
//
#include <hip/hip_runtime.h>

typedef unsigned short u16;
typedef unsigned int u32;
typedef __attribute__((ext_vector_type(4))) float f32x4;
typedef __attribute__((ext_vector_type(16))) float f32x16;
typedef __attribute__((ext_vector_type(8))) short bf16x8;

constexpr int B_ = 2, T_ = 4096, S_ = 4096, G_ = 64, D_ = 1024, H_ = 16, W_ = 512, CHUNK_ = 256;
constexpr int NC_ = T_ / CHUNK_;   // 16 chunks
constexpr int NT_ = (G_ + W_) / 32; // 18 key tiles of 32 (2 global + 16 window)

__device__ __forceinline__ u16 f2bf(float x) {
  u32 u = __builtin_bit_cast(u32, x);
  return (u16)((u + 0x7FFFu + ((u >> 16) & 1u)) >> 16);
}

// ---------------- fused f32 -> bf16 conversion (all 9 segments, one dispatch) ----------------
__global__ __launch_bounds__(256) void cvt_all_kernel(const float* __restrict__ q, const float* __restrict__ e,
                                                      const float* __restrict__ g, const float* __restrict__ w0,
                                                      const float* __restrict__ w1, const float* __restrict__ w2,
                                                      const float* __restrict__ w3, const float* __restrict__ w4,
                                                      const float* __restrict__ w5, u16* __restrict__ dst) {
  int blk = blockIdx.x;
  const float* src;
  int sblk;  // segment start block
  if (blk < 8192) { src = q; sblk = 0; }
  else if (blk < 16384) { src = e; sblk = 8192; }
  else if (blk < 16512) { src = g; sblk = 16384; }
  else if (blk < 17536) { src = w0; sblk = 16512; }
  else if (blk < 18560) { src = w1; sblk = 17536; }
  else if (blk < 19584) { src = w2; sblk = 18560; }
  else if (blk < 20608) { src = w3; sblk = 19584; }
  else if (blk < 21632) { src = w4; sblk = 20608; }
  else { src = w5; sblk = 21632; }
  int li = (blk - sblk) * 256 + threadIdx.x;        // float4 index within segment
  size_t gi = (size_t)blk * 256 + threadIdx.x;      // float4 index within concatenation
  float4 v = ((const float4*)src)[li];
  uint2 o;
  o.x = (u32)f2bf(v.x) | ((u32)f2bf(v.y) << 16);
  o.y = (u32)f2bf(v.z) | ((u32)f2bf(v.w) << 16);
  ((uint2*)dst)[gi] = o;
}

// ---------------- merged projection GEMM: Q + K|V + GK|GV in one launch ----------------
// v6: B operand (weights, L2-hot 256KB panels) loaded DIRECTLY to registers from global
// (double-buffered one K-tile ahead) — its MFMA fragment layout is exactly the row-major
// global layout, so LDS staging of B was pure overhead. LDS now holds only the A ring
// (3 x 16KB = 48KB). One barrier per K-step (was 4), counted vmcnt kept.
// Wait protocol (per-thread vmem issue order, 4 loads per group):
//   prologue: [B0][A0][A1]; tile t: [B(t+1)] vmcnt(8) barrier [stageA(t+2)] 32 MFMA.
//   At tile t's vmcnt(8) the newest 8 = {A(t+1), B(t+1)} -> everything older (B(t),
//   stageA(t)) has landed. Readers of the slot stageA(t+2) overwrites finished their
//   ds_reads before this tile's barrier (consumed by lgkmcnt before MFMA, program order).
//   t==31: vmcnt(0) drain. Tile pairs unrolled so the B double-buffer swaps by name.
// Routing unchanged from r5 (passing): bid<512 K|V; <768 Q (scaled); else GK|GV (M=128).
__global__ __launch_bounds__(256, 2) void proj_kernel(const u16* __restrict__ ex, const u16* __restrict__ qx,
                                                      const u16* __restrict__ gx, const u16* __restrict__ wgt,
                                                      const float* __restrict__ qb, const float* __restrict__ kbias,
                                                      const float* __restrict__ vbias, const float* __restrict__ gkb,
                                                      const float* __restrict__ gvb, u16* __restrict__ q_bf,
                                                      u16* __restrict__ k_bf, u16* __restrict__ gk_bf) {
  __shared__ char lds[49152];  // A ring: 3 x 16KB
  constexpr size_t NW = (size_t)D_ * D_;
  constexpr size_t NQs = (size_t)B_ * T_ * D_;
  constexpr size_t NGs = (size_t)B_ * G_ * D_;
  const int tid = threadIdx.x;
  const int lane = tid & 63;
  const int wid = tid >> 6;
  const int wm = wid >> 1, wn = wid & 1;
  const int l15 = lane & 15, kg = lane >> 4;

  const int bid = blockIdx.x;
  const u16 *A, *Bt;
  const float *b1, *b2;
  u16* out;
  int row0, col0, mloc;
  bool scale = false, dual = false;
  size_t dsplit = 0;
  if (bid < 512) {  // K|V: M=8192, N=2048
    row0 = (bid & 31) * 256; col0 = (bid >> 5) * 128; mloc = 256;
    A = ex; Bt = wgt + NW; b1 = kbias; b2 = vbias; out = k_bf; dsplit = NQs; dual = true;
  } else if (bid < 768) {  // Q: M=8192, N=1024
    int i = bid - 512;
    row0 = (i & 31) * 256; col0 = (i >> 5) * 128; mloc = 256;
    A = qx; Bt = wgt; b1 = qb; b2 = qb; out = q_bf; scale = true;
  } else {  // GK|GV: M=128, N=2048 (rows 128..255 read junk in-bounds, stores guarded)
    int i = bid - 768;
    row0 = 0; col0 = i * 128; mloc = 128;
    A = gx; Bt = wgt + 3 * NW; b1 = gkb; b2 = gvb; out = gk_bf; dsplit = NGs; dual = true;
  }
  const float* bp = b1;
  u16* op = out;
  if (dual && col0 >= 1024) { bp = b2 - 1024; op = out + (dsplit - 1024); }

  f32x4 acc[8][4];
#pragma unroll
  for (int i = 0; i < 8; i++)
#pragma unroll
    for (int j = 0; j < 4; j++)
#pragma unroll
      for (int r = 0; r < 4; r++) acc[i][j][r] = 0.f;

  const char* Abase = (const char*)A;
  const char* Bbase = (const char*)Bt;
  // A staging: source pre-swizzle byte column (XOR chunk with row bits 1-2), linear LDS dest
  const int swb = 16 * ((tid & 3) ^ ((tid >> 3) & 3));

  auto stageA = [&](int slot, int kt) {
#pragma unroll
    for (int p = 0; p < 4; p++) {
      int dst = slot * 16384 + p * 4096 + tid * 16;
      const char* g = Abase + (size_t)(row0 + p * 64 + (tid >> 2)) * 2048 + kt * 64 + swb;
      __builtin_amdgcn_global_load_lds((const __attribute__((address_space(1))) void*)g,
                                       (__attribute__((address_space(3))) void*)(lds + dst), 16, 0, 0);
    }
  };

  // B-fragment global row bases: frag(ni, kt) = 16B at bptr[ni] + kt*64
  const char* bptr[4];
#pragma unroll
  for (int ni = 0; ni < 4; ni++)
    bptr[ni] = Bbase + (size_t)(col0 + wn * 64 + ni * 16 + l15) * 2048 + kg * 16;

  uint4 bA[4], bB[4];
#pragma unroll
  for (int ni = 0; ni < 4; ni++) bA[ni] = *(const uint4*)(bptr[ni]);  // B(0)
  stageA(0, 0);
  stageA(1, 1);

  // one tile: bc = B(t) regs (ready), bn = staging target for B(t+1)
  auto tile = [&](int t, uint4* bc, uint4* bn) {
    if (t + 1 < 32) {
#pragma unroll
      for (int ni = 0; ni < 4; ni++) bn[ni] = *(const uint4*)(bptr[ni] + (size_t)(t + 1) * 64);
    }
    if (t < 31) {
      asm volatile("s_waitcnt vmcnt(8)" ::: "memory");
    } else {
      asm volatile("s_waitcnt vmcnt(0)" ::: "memory");
    }
    __builtin_amdgcn_s_barrier();
    if (t + 2 < 32) stageA((t + 2) % 3, t + 2);

    const char* Ab = lds + (t % 3) * 16384;
    bf16x8 bq[4];
#pragma unroll
    for (int ni = 0; ni < 4; ni++) bq[ni] = __builtin_bit_cast(bf16x8, bc[ni]);
    bf16x8 af[4];
#pragma unroll
    for (int mi = 0; mi < 4; mi++) {
      int r = wm * 128 + mi * 16 + l15;
      af[mi] = *(const bf16x8*)(Ab + ((r * 64 + kg * 16) ^ (((r >> 1) & 3) << 4)));
    }
    __builtin_amdgcn_s_setprio(1);
#pragma unroll
    for (int mi = 0; mi < 4; mi++)
#pragma unroll
      for (int ni = 0; ni < 4; ni++)
        acc[mi][ni] = __builtin_amdgcn_mfma_f32_16x16x32_bf16(bq[ni], af[mi], acc[mi][ni], 0, 0, 0);
    __builtin_amdgcn_s_setprio(0);
#pragma unroll
    for (int mi = 0; mi < 4; mi++) {
      int r = wm * 128 + (mi + 4) * 16 + l15;
      af[mi] = *(const bf16x8*)(Ab + ((r * 64 + kg * 16) ^ (((r >> 1) & 3) << 4)));
    }
    __builtin_amdgcn_s_setprio(1);
#pragma unroll
    for (int mi = 0; mi < 4; mi++)
#pragma unroll
      for (int ni = 0; ni < 4; ni++)
        acc[mi + 4][ni] = __builtin_amdgcn_mfma_f32_16x16x32_bf16(bq[ni], af[mi], acc[mi + 4][ni], 0, 0, 0);
    __builtin_amdgcn_s_setprio(0);
  };

  for (int tt = 0; tt < 32; tt += 2) {
    tile(tt, bA, bB);
    tile(tt + 1, bB, bA);
  }

  // epilogue: C[row0+wm*128+mi*16+l15][col0+wn*64+ni*16+kg*4+r], store guarded by mloc
  float4 bv4[4];
#pragma unroll
  for (int ni = 0; ni < 4; ni++) bv4[ni] = *(const float4*)&bp[col0 + wn * 64 + ni * 16 + kg * 4];
#pragma unroll
  for (int mi = 0; mi < 8; mi++) {
    int rloc = wm * 128 + mi * 16 + l15;
    if (rloc >= mloc) continue;  // wave-uniform (mloc=128 cuts exactly wm==1)
    size_t grow = (size_t)(row0 + rloc);
#pragma unroll
    for (int ni = 0; ni < 4; ni++) {
      int gcol = col0 + wn * 64 + ni * 16 + kg * 4;
      float v0 = acc[mi][ni][0] + bv4[ni].x;
      float v1 = acc[mi][ni][1] + bv4[ni].y;
      float v2 = acc[mi][ni][2] + bv4[ni].z;
      float v3 = acc[mi][ni][3] + bv4[ni].w;
      if (scale) {
        v0 *= 0.18033688011112042f; v1 *= 0.18033688011112042f;  // (1/8)*log2(e)
        v2 *= 0.18033688011112042f; v3 *= 0.18033688011112042f;
      }
      uint2 o;
      asm("v_cvt_pk_bf16_f32 %0, %1, %2" : "=v"(o.x) : "v"(v0), "v"(v1));
      asm("v_cvt_pk_bf16_f32 %0, %1, %2" : "=v"(o.y) : "v"(v2), "v"(v3));
      *(uint2*)&op[grow * 1024 + gcol] = o;
    }
  }
}

// ---------------- bf16 GEMM 128x128 (v3, passing): used for O projection ----------------
// MODE 2: f32 out (only instantiated mode)
template <int MODE>
__global__ __launch_bounds__(256) void gemm_kernel(const u16* __restrict__ A, const u16* __restrict__ Bt,
                                                   const float* __restrict__ bias, const float* __restrict__ bias2,
                                                   size_t split, void* __restrict__ out) {
  __shared__ char lds[32768];
  char* As = lds;
  char* Bs = lds + 16384;
  const int tid = threadIdx.x;
  const int lane = tid & 63;
  const int wv = tid >> 6;
  const int wr = wv >> 1, wc = wv & 1;
  const int l15 = lane & 15, kg = lane >> 4;
  const int row0 = blockIdx.x * 128;
  const int col0 = blockIdx.y * 128;

  f32x4 acc[4][4];
#pragma unroll
  for (int i = 0; i < 4; i++)
#pragma unroll
    for (int j = 0; j < 4; j++)
#pragma unroll
      for (int r = 0; r < 4; r++) acc[i][j][r] = 0.f;

  const char* Abase = (const char*)A;
  const char* Bbase = (const char*)Bt;

  const int kb = 16 * ((lane & 3) ^ ((lane >> 3) & 3));
  auto stage = [&](int bufsel, int k0) {
#pragma unroll
    for (int c = 0; c < 2; c++) {
      int arow = wv * 32 + c * 16 + (lane >> 2);
      int dsto = bufsel * 8192 + wv * 2048 + c * 1024 + lane * 16;
      const char* ga = Abase + ((size_t)(row0 + arow) * 2048 + (size_t)k0 * 2 + kb);
      __builtin_amdgcn_global_load_lds((const __attribute__((address_space(1))) void*)ga,
                                       (__attribute__((address_space(3))) void*)(As + dsto), 16, 0, 0);
      const char* gb = Bbase + ((size_t)(col0 + arow) * 2048 + (size_t)k0 * 2 + kb);
      __builtin_amdgcn_global_load_lds((const __attribute__((address_space(1))) void*)gb,
                                       (__attribute__((address_space(3))) void*)(Bs + dsto), 16, 0, 0);
    }
  };

  stage(0, 0);
  __syncthreads();

  for (int it = 0; it < 32; ++it) {
    const int cur = it & 1;
    if (it + 1 < 32) stage(cur ^ 1, (it + 1) * 32);

    const char* Ab = As + cur * 8192;
    const char* Bb = Bs + cur * 8192;
    bf16x8 af[4], bfv[4];
#pragma unroll
    for (int mi = 0; mi < 4; mi++) {
      int row = wr * 64 + mi * 16 + l15;
      af[mi] = *(const bf16x8*)(Ab + ((row * 64 + kg * 16) ^ ((row & 6) << 3)));
    }
#pragma unroll
    for (int ni = 0; ni < 4; ni++) {
      int row = wc * 64 + ni * 16 + l15;
      bfv[ni] = *(const bf16x8*)(Bb + ((row * 64 + kg * 16) ^ ((row & 6) << 3)));
    }
    __builtin_amdgcn_s_setprio(1);
#pragma unroll
    for (int mi = 0; mi < 4; mi++)
#pragma unroll
      for (int ni = 0; ni < 4; ni++)
        acc[mi][ni] = __builtin_amdgcn_mfma_f32_16x16x32_bf16(bfv[ni], af[mi], acc[mi][ni], 0, 0, 0);
    __builtin_amdgcn_s_setprio(0);
    __syncthreads();
  }

  const float* bp = bias;
  (void)bias2; (void)split;
  float4 bv4[4];
#pragma unroll
  for (int ni = 0; ni < 4; ni++) bv4[ni] = *(const float4*)&bp[col0 + wc * 64 + ni * 16 + kg * 4];
#pragma unroll
  for (int mi = 0; mi < 4; mi++) {
    size_t grow = (size_t)(row0 + wr * 64 + mi * 16 + l15);
#pragma unroll
    for (int ni = 0; ni < 4; ni++) {
      int gcol = col0 + wc * 64 + ni * 16 + kg * 4;
      float v0 = acc[mi][ni][0] + bv4[ni].x;
      float v1 = acc[mi][ni][1] + bv4[ni].y;
      float v2 = acc[mi][ni][2] + bv4[ni].z;
      float v3 = acc[mi][ni][3] + bv4[ni].w;
      if (MODE == 2) {
        float4 fo = {v0, v1, v2, v3};
        *(float4*)&((float*)out)[grow * 1024 + gcol] = fo;
      } else {
        uint2 o;
        asm("v_cvt_pk_bf16_f32 %0, %1, %2" : "=v"(o.x) : "v"(v0), "v"(v1));
        asm("v_cvt_pk_bf16_f32 %0, %1, %2" : "=v"(o.y) : "v"(v2), "v"(v3));
        *(uint2*)&((u16*)out)[grow * 1024 + gcol] = o;
      }
    }
  }
}

// ---------------- fused attention (unchanged, passing) ----------------
__global__ __launch_bounds__(512, 4) void attn_kernel(const u16* __restrict__ q_bf, const u16* __restrict__ k_bf,
                                                      const u16* __restrict__ v_bf, const u16* __restrict__ gk_bf,
                                                      const u16* __restrict__ gv_bf, u16* __restrict__ ao,
                                                      const int* __restrict__ rptr) {
  __shared__ u16 smem[16384];
  const int c = blockIdx.x, h = blockIdx.y, b = blockIdx.z;
  const int tid = threadIdx.x;
  const int lane = tid & 63, wv = tid >> 6;
  const int l31 = lane & 31, half = lane >> 5;
  const int t0 = c * CHUNK_;

  int rr = rptr[0];
  int centert = c * CHUNK_ + CHUNK_ / 2;
  int expected = (int)((float)centert / (float)rr);
  expected = min(max(expected, 0), S_ - 1);
  int ws0 = min(max(expected - W_ / 2, 0), S_ - W_);

  bf16x8 qf[4];
  {
    const u16* qrow = q_bf + ((size_t)(b * T_ + t0 + wv * 32 + l31)) * D_ + h * 64 + half * 8;
#pragma unroll
    for (int s = 0; s < 4; s++) qf[s] = *(const bf16x8*)(qrow + s * 16);
  }

  const int skey = (tid & 255) >> 3, shq = tid & 7;
  const bool isK = tid < 256;

  auto load_tile = [&](int j) -> uint4 {
    const u16* base;
    size_t row;
    if (j < 2) {
      base = isK ? gk_bf : gv_bf;
      row = (size_t)(b * G_ + j * 32 + skey);
    } else {
      base = isK ? k_bf : v_bf;
      row = (size_t)(b * S_ + ws0 + (j - 2) * 32 + skey);
    }
    return *(const uint4*)(base + row * D_ + h * 64 + shq * 8);
  };

  f32x16 oacc[2];
#pragma unroll
  for (int i = 0; i < 2; i++)
#pragma unroll
    for (int r = 0; r < 16; r++) oacc[i][r] = 0.f;
  float mrun = -1e30f, lsum = 0.f;

  uint4 stg = load_tile(0);

  for (int j = 0; j < NT_; j++) {
    const int bsel = j & 1;
    if (isK) {
      *(uint4*)((char*)smem + bsel * 4096 + ((skey * 128 + shq * 16) ^ ((skey & 7) << 4))) = stg;
    } else {
      const u16* pv = (const u16*)&stg;
      char* bp = (char*)smem + 8192 + bsel * 5248 + shq * 656 + skey * 2;  // 656 = 8*80+16 (row skew)
#pragma unroll
      for (int e = 0; e < 8; e++) *(u16*)(bp + e * 80) = pv[e];
    }
    if (j + 1 < NT_) stg = load_tile(j + 1);
    __syncthreads();

    const int kbase = bsel * 4096;
    const int vtb = 8192 + bsel * 5248;

    f32x16 sacc;
#pragma unroll
    for (int r = 0; r < 16; r++) sacc[r] = 0.f;
    __builtin_amdgcn_s_setprio(1);
#pragma unroll
    for (int s = 0; s < 4; s++) {
      int kbx = kbase + ((l31 * 128 + half * 16 + s * 32) ^ ((l31 & 7) << 4));
      bf16x8 kf = *(const bf16x8*)((char*)smem + kbx);
      sacc = __builtin_amdgcn_mfma_f32_32x32x16_bf16(kf, qf[s], sacc, 0, 0, 0);
    }
    __builtin_amdgcn_s_setprio(0);

    float t0m = fmaxf(fmaxf(sacc[0], sacc[1]), sacc[2]);
    float t1m = fmaxf(fmaxf(sacc[3], sacc[4]), sacc[5]);
    float t2m = fmaxf(fmaxf(sacc[6], sacc[7]), sacc[8]);
    float t3m = fmaxf(fmaxf(sacc[9], sacc[10]), sacc[11]);
    float t4m = fmaxf(fmaxf(sacc[12], sacc[13]), sacc[14]);
    float tmax = fmaxf(fmaxf(fmaxf(t0m, t1m), fmaxf(t2m, t3m)), fmaxf(t4m, sacc[15]));
    tmax = fmaxf(tmax, __shfl_xor(tmax, 32));
    if (__any(tmax > mrun + 8.f)) {
      float mnew = fmaxf(mrun, tmax);
      float fac = __builtin_amdgcn_exp2f(mrun - mnew);
      mrun = mnew;
      lsum *= fac;
#pragma unroll
      for (int i = 0; i < 2; i++)
#pragma unroll
        for (int r = 0; r < 16; r++) oacc[i][r] *= fac;
    }
    float p[16];
#pragma unroll
    for (int r = 0; r < 16; r++) p[r] = __builtin_amdgcn_exp2f(sacc[r] - mrun);
    float s0s = (p[0] + p[1]) + (p[2] + p[3]);
    float s1s = (p[4] + p[5]) + (p[6] + p[7]);
    float s2s = (p[8] + p[9]) + (p[10] + p[11]);
    float s3s = (p[12] + p[13]) + (p[14] + p[15]);
    float tsum = (s0s + s1s) + (s2s + s3s);
    tsum += __shfl_xor(tsum, 32);
    lsum += tsum;

    u32 xs[8], px[8];
#pragma unroll
    for (int i = 0; i < 8; i++)
      asm("v_cvt_pk_bf16_f32 %0, %1, %2" : "=v"(xs[i]) : "v"(p[2 * i]), "v"(p[2 * i + 1]));
#pragma unroll
    for (int i = 0; i < 8; i++) px[i] = (u32)__shfl_xor((int)xs[i], 32);
    u32 Bk[2][4];
    Bk[0][0] = half ? px[2] : xs[0];
    Bk[0][1] = half ? px[3] : xs[1];
    Bk[0][2] = half ? xs[2] : px[0];
    Bk[0][3] = half ? xs[3] : px[1];
    Bk[1][0] = half ? px[6] : xs[4];
    Bk[1][1] = half ? px[7] : xs[5];
    Bk[1][2] = half ? xs[6] : px[4];
    Bk[1][3] = half ? xs[7] : px[5];

    int vro = vtb + l31 * 80 + ((l31 >> 3) << 4) + half * 16;
    __builtin_amdgcn_s_setprio(1);
#pragma unroll
    for (int hdf = 0; hdf < 2; hdf++) {
#pragma unroll
      for (int ks = 0; ks < 2; ks++) {
        bf16x8 vf = *(const bf16x8*)((const char*)smem + vro + hdf * 2624 + ks * 32);  // 2624 = 32*80+64
        uint4 u4;
        u4.x = Bk[ks][0]; u4.y = Bk[ks][1]; u4.z = Bk[ks][2]; u4.w = Bk[ks][3];
        bf16x8 pb = __builtin_bit_cast(bf16x8, u4);
        oacc[hdf] = __builtin_amdgcn_mfma_f32_32x32x16_bf16(vf, pb, oacc[hdf], 0, 0, 0);
      }
    }
    __builtin_amdgcn_s_setprio(0);
  }

  __syncthreads();
  float inv = 1.f / lsum;
#pragma unroll
  for (int hdf = 0; hdf < 2; hdf++) {
#pragma unroll
    for (int a = 0; a < 4; a++) {
      float f0 = oacc[hdf][4 * a] * inv, f1 = oacc[hdf][4 * a + 1] * inv;
      float f2 = oacc[hdf][4 * a + 2] * inv, f3 = oacc[hdf][4 * a + 3] * inv;
      uint2 o;
      asm("v_cvt_pk_bf16_f32 %0, %1, %2" : "=v"(o.x) : "v"(f0), "v"(f1));
      asm("v_cvt_pk_bf16_f32 %0, %1, %2" : "=v"(o.y) : "v"(f2), "v"(f3));
      int off = wv * 4096 + l31 * 128 + ((16 * a + 8 * half + 64 * hdf) ^ ((l31 & 7) << 4));
      *(uint2*)((char*)smem + off) = o;
    }
  }
  __syncthreads();
#pragma unroll
  for (int it = 0; it < 4; it++) {
    int byteo = (tid + it * 512) * 16;
    int row = byteo >> 7;
    int colb = byteo & 127;
    uint4 vv = *(const uint4*)((const char*)smem + row * 128 + (colb ^ ((row & 7) << 4)));
    *(uint4*)(ao + ((size_t)(b * T_ + t0 + row)) * D_ + h * 64 + (colb >> 1)) = vv;
  }
}

extern "C" void kernel_launch(void* const* d_in, const int* in_sizes, int n_in,
                              void* d_out, int out_size, void* d_ws, size_t ws_size,
                              hipStream_t stream) {
  (void)in_sizes; (void)n_in; (void)out_size; (void)ws_size;
  const float* query = (const float*)d_in[0];
  const float* enc = (const float*)d_in[1];
  const float* glob = (const float*)d_in[2];
  const float* qw = (const float*)d_in[3];
  const float* qb = (const float*)d_in[4];
  const float* kw = (const float*)d_in[5];
  const float* kb = (const float*)d_in[6];
  const float* vw = (const float*)d_in[7];
  const float* vb = (const float*)d_in[8];
  const float* gkw = (const float*)d_in[9];
  const float* gkb = (const float*)d_in[10];
  const float* gvw = (const float*)d_in[11];
  const float* gvb = (const float*)d_in[12];
  const float* ow = (const float*)d_in[13];
  const float* ob = (const float*)d_in[14];
  const int* rp = (const int*)d_in[15];

  const size_t NQ = (size_t)B_ * T_ * D_;   // 8388608
  const size_t NG = (size_t)B_ * G_ * D_;   // 131072
  const size_t NW = (size_t)D_ * D_;        // 1048576

  u16* ws = (u16*)d_ws;
  u16* qx = ws;                // bf16 query
  u16* ex = qx + NQ;           // bf16 encoder_out
  u16* gx = ex + NQ;           // bf16 global_tokens
  u16* wgt = gx + NG;          // 6 weights bf16 (qw,kw,vw,gkw,gvw,ow) — contiguous
  u16* q_bf = wgt + 6 * NW;    // projected q (pre-scaled by 0.125*log2e)
  u16* k_bf = q_bf + NQ;
  u16* v_bf = k_bf + NQ;       // contiguous after k_bf (fused K|V)
  u16* gk_bf = v_bf + NQ;
  u16* gv_bf = gk_bf + NG;     // contiguous after gk_bf (fused GK|GV)
  u16* ao = gv_bf + NG;        // attention output bf16 [B*T, D]

  // one fused conversion dispatch: 8192+8192+128+6*1024 = 22656 blocks
  cvt_all_kernel<<<22656, 256, 0, stream>>>(query, enc, glob, qw, kw, vw, gkw, gvw, ow, ws);

  // merged Q + K|V + GK|GV projection: 512 + 256 + 16 = 784 blocks
  proj_kernel<<<784, 256, 0, stream>>>(ex, qx, gx, wgt, qb, kb, vb, gkb, gvb, q_bf, k_bf, gk_bf);

  attn_kernel<<<dim3(NC_, H_, B_), 512, 0, stream>>>(q_bf, k_bf, v_bf, gk_bf, gv_bf, ao, rp);

  gemm_kernel<2><<<dim3(64, 8), 256, 0, stream>>>(ao, wgt + 5 * NW, ob, ob, 0, d_out);
}

// Round 7
// 151.765 us; speedup vs baseline: 1.2100x; 1.2100x over previous
//
#include <hip/hip_runtime.h>

typedef unsigned short u16;
typedef unsigned int u32;
typedef __attribute__((ext_vector_type(4))) float f32x4;
typedef __attribute__((ext_vector_type(16))) float f32x16;
typedef __attribute__((ext_vector_type(8))) short bf16x8;

constexpr int B_ = 2, T_ = 4096, S_ = 4096, G_ = 64, D_ = 1024, H_ = 16, W_ = 512, CHUNK_ = 256;
constexpr int NC_ = T_ / CHUNK_;   // 16 chunks
constexpr int NT_ = (G_ + W_) / 32; // 18 key tiles of 32 (2 global + 16 window)

__device__ __forceinline__ u16 f2bf(float x) {
  u32 u = __builtin_bit_cast(u32, x);
  return (u16)((u + 0x7FFFu + ((u >> 16) & 1u)) >> 16);
}

// ---------------- fused f32 -> bf16 conversion (all 9 segments, one dispatch) ----------------
__global__ __launch_bounds__(256) void cvt_all_kernel(const float* __restrict__ q, const float* __restrict__ e,
                                                      const float* __restrict__ g, const float* __restrict__ w0,
                                                      const float* __restrict__ w1, const float* __restrict__ w2,
                                                      const float* __restrict__ w3, const float* __restrict__ w4,
                                                      const float* __restrict__ w5, u16* __restrict__ dst) {
  int blk = blockIdx.x;
  const float* src;
  int sblk;  // segment start block
  if (blk < 8192) { src = q; sblk = 0; }
  else if (blk < 16384) { src = e; sblk = 8192; }
  else if (blk < 16512) { src = g; sblk = 16384; }
  else if (blk < 17536) { src = w0; sblk = 16512; }
  else if (blk < 18560) { src = w1; sblk = 17536; }
  else if (blk < 19584) { src = w2; sblk = 18560; }
  else if (blk < 20608) { src = w3; sblk = 19584; }
  else if (blk < 21632) { src = w4; sblk = 20608; }
  else { src = w5; sblk = 21632; }
  int li = (blk - sblk) * 256 + threadIdx.x;        // float4 index within segment
  size_t gi = (size_t)blk * 256 + threadIdx.x;      // float4 index within concatenation
  float4 v = ((const float4*)src)[li];
  uint2 o;
  o.x = (u32)f2bf(v.x) | ((u32)f2bf(v.y) << 16);
  o.y = (u32)f2bf(v.z) | ((u32)f2bf(v.w) << 16);
  ((uint2*)dst)[gi] = o;
}

// ---------------- merged projection GEMM: Q + K|V + GK|GV (r5-verified ring kernel) ----------------
// Tile 256x128, 256 threads = 4 waves (2M x 2N). LDS 72KB ring-3 (A 16KB + B 8KB per slot),
// prefetch issued 2 tiles ahead; counted s_waitcnt vmcnt(6) at tile boundary, vmcnt(0) only at
// drain. Source-pre-swizzled global_load_lds staging (coalesced; r6 lesson: operand loads must
// be lane-contiguous — LDS staging is what converts coalesced->per-lane-fragment).
__global__ __launch_bounds__(256, 2) void proj_kernel(const u16* __restrict__ ex, const u16* __restrict__ qx,
                                                      const u16* __restrict__ gx, const u16* __restrict__ wgt,
                                                      const float* __restrict__ qb, const float* __restrict__ kbias,
                                                      const float* __restrict__ vbias, const float* __restrict__ gkb,
                                                      const float* __restrict__ gvb, u16* __restrict__ q_bf,
                                                      u16* __restrict__ k_bf, u16* __restrict__ gk_bf) {
  __shared__ char lds[73728];  // A ring [0,49152): 3 x 16KB; B ring [49152,73728): 3 x 8KB
  constexpr size_t NW = (size_t)D_ * D_;
  constexpr size_t NQs = (size_t)B_ * T_ * D_;
  constexpr size_t NGs = (size_t)B_ * G_ * D_;
  const int tid = threadIdx.x;
  const int lane = tid & 63;
  const int wid = tid >> 6;
  const int wm = wid >> 1, wn = wid & 1;
  const int l15 = lane & 15, kg = lane >> 4;

  const int bid = blockIdx.x;
  const u16 *A, *Bt;
  const float *b1, *b2;
  u16* out;
  int row0, col0, mloc;
  bool scale = false, dual = false;
  size_t dsplit = 0;
  if (bid < 512) {  // K|V: M=8192, N=2048
    row0 = (bid & 31) * 256; col0 = (bid >> 5) * 128; mloc = 256;
    A = ex; Bt = wgt + NW; b1 = kbias; b2 = vbias; out = k_bf; dsplit = NQs; dual = true;
  } else if (bid < 768) {  // Q: M=8192, N=1024
    int i = bid - 512;
    row0 = (i & 31) * 256; col0 = (i >> 5) * 128; mloc = 256;
    A = qx; Bt = wgt; b1 = qb; b2 = qb; out = q_bf; scale = true;
  } else {  // GK|GV: M=128, N=2048 (rows 128..255 read junk in-bounds, stores guarded)
    int i = bid - 768;
    row0 = 0; col0 = i * 128; mloc = 128;
    A = gx; Bt = wgt + 3 * NW; b1 = gkb; b2 = gvb; out = gk_bf; dsplit = NGs; dual = true;
  }
  const float* bp = b1;
  u16* op = out;
  if (dual && col0 >= 1024) { bp = b2 - 1024; op = out + (dsplit - 1024); }

  f32x4 acc[8][4];
#pragma unroll
  for (int i = 0; i < 8; i++)
#pragma unroll
    for (int j = 0; j < 4; j++)
#pragma unroll
      for (int r = 0; r < 4; r++) acc[i][j][r] = 0.f;

  const char* Abase = (const char*)A;
  const char* Bbase = (const char*)Bt;
  // source pre-swizzle byte column (XOR chunk with row bits 1-2); row = pass*64 + tid>>2
  const int swb = 16 * ((tid & 3) ^ ((tid >> 3) & 3));

  auto stageA = [&](int slot, int kt) {
#pragma unroll
    for (int p = 0; p < 4; p++) {
      int dst = slot * 16384 + p * 4096 + tid * 16;
      const char* g = Abase + (size_t)(row0 + p * 64 + (tid >> 2)) * 2048 + kt * 64 + swb;
      __builtin_amdgcn_global_load_lds((const __attribute__((address_space(1))) void*)g,
                                       (__attribute__((address_space(3))) void*)(lds + dst), 16, 0, 0);
    }
  };
  auto stageB = [&](int slot, int kt) {
#pragma unroll
    for (int p = 0; p < 2; p++) {
      int dst = 49152 + slot * 8192 + p * 4096 + tid * 16;
      const char* g = Bbase + (size_t)(col0 + p * 64 + (tid >> 2)) * 2048 + kt * 64 + swb;
      __builtin_amdgcn_global_load_lds((const __attribute__((address_space(1))) void*)g,
                                       (__attribute__((address_space(3))) void*)(lds + dst), 16, 0, 0);
    }
  };

  // prologue: stage tiles 0,1 (12 loads); vmcnt(6) -> tile0's 6 loads landed
  stageA(0, 0); stageB(0, 0);
  stageA(1, 1); stageB(1, 1);
  asm volatile("s_waitcnt vmcnt(6)" ::: "memory");
  __builtin_amdgcn_s_barrier();

  int cur = 0, nx = 2;
  for (int t = 0; t < 32; ++t) {
    const char* Ab = lds + cur * 16384;
    const char* Bb = lds + 49152 + cur * 8192;
    bf16x8 af[4];
    bf16x8 bq[4];
    // ---- phase 0: read B frags (reused both phases) + A frags mi 0..3; stage A(t+2)
#pragma unroll
    for (int ni = 0; ni < 4; ni++) {
      int r = wn * 64 + ni * 16 + l15;
      bq[ni] = *(const bf16x8*)(Bb + ((r * 64 + kg * 16) ^ (((r >> 1) & 3) << 4)));
    }
#pragma unroll
    for (int mi = 0; mi < 4; mi++) {
      int r = wm * 128 + mi * 16 + l15;
      af[mi] = *(const bf16x8*)(Ab + ((r * 64 + kg * 16) ^ (((r >> 1) & 3) << 4)));
    }
    if (t + 2 < 32) stageA(nx, t + 2);
    __builtin_amdgcn_s_barrier();
    __builtin_amdgcn_s_setprio(1);
#pragma unroll
    for (int mi = 0; mi < 4; mi++)
#pragma unroll
      for (int ni = 0; ni < 4; ni++)
        acc[mi][ni] = __builtin_amdgcn_mfma_f32_16x16x32_bf16(bq[ni], af[mi], acc[mi][ni], 0, 0, 0);
    __builtin_amdgcn_s_setprio(0);
    __builtin_amdgcn_s_barrier();
    // ---- phase 1: read A frags mi 4..7; stage B(t+2)
#pragma unroll
    for (int mi = 0; mi < 4; mi++) {
      int r = wm * 128 + (mi + 4) * 16 + l15;
      af[mi] = *(const bf16x8*)(Ab + ((r * 64 + kg * 16) ^ (((r >> 1) & 3) << 4)));
    }
    if (t + 2 < 32) stageB(nx, t + 2);
    __builtin_amdgcn_s_barrier();
    __builtin_amdgcn_s_setprio(1);
#pragma unroll
    for (int mi = 0; mi < 4; mi++)
#pragma unroll
      for (int ni = 0; ni < 4; ni++)
        acc[mi + 4][ni] = __builtin_amdgcn_mfma_f32_16x16x32_bf16(bq[ni], af[mi], acc[mi + 4][ni], 0, 0, 0);
    __builtin_amdgcn_s_setprio(0);
    // tile boundary: stage(t+1) landed for all (vmcnt(6) = only stage(t+2)'s 6 in flight)
    if (t < 30) {
      asm volatile("s_waitcnt vmcnt(6)" ::: "memory");
    } else if (t == 30) {
      asm volatile("s_waitcnt vmcnt(0)" ::: "memory");
    }
    __builtin_amdgcn_s_barrier();
    cur = cur == 2 ? 0 : cur + 1;
    nx = nx == 2 ? 0 : nx + 1;
  }

  // epilogue: C[row0+wm*128+mi*16+l15][col0+wn*64+ni*16+kg*4+r], store guarded by mloc
  float4 bv4[4];
#pragma unroll
  for (int ni = 0; ni < 4; ni++) bv4[ni] = *(const float4*)&bp[col0 + wn * 64 + ni * 16 + kg * 4];
#pragma unroll
  for (int mi = 0; mi < 8; mi++) {
    int rloc = wm * 128 + mi * 16 + l15;
    if (rloc >= mloc) continue;  // wave-uniform (mloc=128 cuts exactly wm==1)
    size_t grow = (size_t)(row0 + rloc);
#pragma unroll
    for (int ni = 0; ni < 4; ni++) {
      int gcol = col0 + wn * 64 + ni * 16 + kg * 4;
      float v0 = acc[mi][ni][0] + bv4[ni].x;
      float v1 = acc[mi][ni][1] + bv4[ni].y;
      float v2 = acc[mi][ni][2] + bv4[ni].z;
      float v3 = acc[mi][ni][3] + bv4[ni].w;
      if (scale) {
        v0 *= 0.18033688011112042f; v1 *= 0.18033688011112042f;  // (1/8)*log2(e)
        v2 *= 0.18033688011112042f; v3 *= 0.18033688011112042f;
      }
      uint2 o;
      asm("v_cvt_pk_bf16_f32 %0, %1, %2" : "=v"(o.x) : "v"(v0), "v"(v1));
      asm("v_cvt_pk_bf16_f32 %0, %1, %2" : "=v"(o.y) : "v"(v2), "v"(v3));
      *(uint2*)&op[grow * 1024 + gcol] = o;
    }
  }
}

// ---------------- O-projection GEMM: same r5-verified ring structure, f32 epilogue ----------------
// M=8192, N=1024, 256x128 tiles -> 256 blocks (~1/CU). A = ao (bf16), Bt = ow (bf16), out f32.
__global__ __launch_bounds__(256, 2) void gemmO_kernel(const u16* __restrict__ A, const u16* __restrict__ Bt,
                                                       const float* __restrict__ bias, float* __restrict__ out) {
  __shared__ char lds[73728];  // A ring [0,49152): 3 x 16KB; B ring [49152,73728): 3 x 8KB
  const int tid = threadIdx.x;
  const int lane = tid & 63;
  const int wid = tid >> 6;
  const int wm = wid >> 1, wn = wid & 1;
  const int l15 = lane & 15, kg = lane >> 4;

  const int bid = blockIdx.x;
  const int row0 = (bid & 31) * 256;
  const int col0 = (bid >> 5) * 128;

  f32x4 acc[8][4];
#pragma unroll
  for (int i = 0; i < 8; i++)
#pragma unroll
    for (int j = 0; j < 4; j++)
#pragma unroll
      for (int r = 0; r < 4; r++) acc[i][j][r] = 0.f;

  const char* Abase = (const char*)A;
  const char* Bbase = (const char*)Bt;
  const int swb = 16 * ((tid & 3) ^ ((tid >> 3) & 3));

  auto stageA = [&](int slot, int kt) {
#pragma unroll
    for (int p = 0; p < 4; p++) {
      int dst = slot * 16384 + p * 4096 + tid * 16;
      const char* g = Abase + (size_t)(row0 + p * 64 + (tid >> 2)) * 2048 + kt * 64 + swb;
      __builtin_amdgcn_global_load_lds((const __attribute__((address_space(1))) void*)g,
                                       (__attribute__((address_space(3))) void*)(lds + dst), 16, 0, 0);
    }
  };
  auto stageB = [&](int slot, int kt) {
#pragma unroll
    for (int p = 0; p < 2; p++) {
      int dst = 49152 + slot * 8192 + p * 4096 + tid * 16;
      const char* g = Bbase + (size_t)(col0 + p * 64 + (tid >> 2)) * 2048 + kt * 64 + swb;
      __builtin_amdgcn_global_load_lds((const __attribute__((address_space(1))) void*)g,
                                       (__attribute__((address_space(3))) void*)(lds + dst), 16, 0, 0);
    }
  };

  stageA(0, 0); stageB(0, 0);
  stageA(1, 1); stageB(1, 1);
  asm volatile("s_waitcnt vmcnt(6)" ::: "memory");
  __builtin_amdgcn_s_barrier();

  int cur = 0, nx = 2;
  for (int t = 0; t < 32; ++t) {
    const char* Ab = lds + cur * 16384;
    const char* Bb = lds + 49152 + cur * 8192;
    bf16x8 af[4];
    bf16x8 bq[4];
#pragma unroll
    for (int ni = 0; ni < 4; ni++) {
      int r = wn * 64 + ni * 16 + l15;
      bq[ni] = *(const bf16x8*)(Bb + ((r * 64 + kg * 16) ^ (((r >> 1) & 3) << 4)));
    }
#pragma unroll
    for (int mi = 0; mi < 4; mi++) {
      int r = wm * 128 + mi * 16 + l15;
      af[mi] = *(const bf16x8*)(Ab + ((r * 64 + kg * 16) ^ (((r >> 1) & 3) << 4)));
    }
    if (t + 2 < 32) stageA(nx, t + 2);
    __builtin_amdgcn_s_barrier();
    __builtin_amdgcn_s_setprio(1);
#pragma unroll
    for (int mi = 0; mi < 4; mi++)
#pragma unroll
      for (int ni = 0; ni < 4; ni++)
        acc[mi][ni] = __builtin_amdgcn_mfma_f32_16x16x32_bf16(bq[ni], af[mi], acc[mi][ni], 0, 0, 0);
    __builtin_amdgcn_s_setprio(0);
    __builtin_amdgcn_s_barrier();
#pragma unroll
    for (int mi = 0; mi < 4; mi++) {
      int r = wm * 128 + (mi + 4) * 16 + l15;
      af[mi] = *(const bf16x8*)(Ab + ((r * 64 + kg * 16) ^ (((r >> 1) & 3) << 4)));
    }
    if (t + 2 < 32) stageB(nx, t + 2);
    __builtin_amdgcn_s_barrier();
    __builtin_amdgcn_s_setprio(1);
#pragma unroll
    for (int mi = 0; mi < 4; mi++)
#pragma unroll
      for (int ni = 0; ni < 4; ni++)
        acc[mi + 4][ni] = __builtin_amdgcn_mfma_f32_16x16x32_bf16(bq[ni], af[mi], acc[mi + 4][ni], 0, 0, 0);
    __builtin_amdgcn_s_setprio(0);
    if (t < 30) {
      asm volatile("s_waitcnt vmcnt(6)" ::: "memory");
    } else if (t == 30) {
      asm volatile("s_waitcnt vmcnt(0)" ::: "memory");
    }
    __builtin_amdgcn_s_barrier();
    cur = cur == 2 ? 0 : cur + 1;
    nx = nx == 2 ? 0 : nx + 1;
  }

  float4 bv4[4];
#pragma unroll
  for (int ni = 0; ni < 4; ni++) bv4[ni] = *(const float4*)&bias[col0 + wn * 64 + ni * 16 + kg * 4];
#pragma unroll
  for (int mi = 0; mi < 8; mi++) {
    size_t grow = (size_t)(row0 + wm * 128 + mi * 16 + l15);
#pragma unroll
    for (int ni = 0; ni < 4; ni++) {
      int gcol = col0 + wn * 64 + ni * 16 + kg * 4;
      float4 fo;
      fo.x = acc[mi][ni][0] + bv4[ni].x;
      fo.y = acc[mi][ni][1] + bv4[ni].y;
      fo.z = acc[mi][ni][2] + bv4[ni].z;
      fo.w = acc[mi][ni][3] + bv4[ni].w;
      *(float4*)&out[grow * 1024 + gcol] = fo;
    }
  }
}

// ---------------- fused attention (unchanged, passing) ----------------
__global__ __launch_bounds__(512, 4) void attn_kernel(const u16* __restrict__ q_bf, const u16* __restrict__ k_bf,
                                                      const u16* __restrict__ v_bf, const u16* __restrict__ gk_bf,
                                                      const u16* __restrict__ gv_bf, u16* __restrict__ ao,
                                                      const int* __restrict__ rptr) {
  __shared__ u16 smem[16384];
  const int c = blockIdx.x, h = blockIdx.y, b = blockIdx.z;
  const int tid = threadIdx.x;
  const int lane = tid & 63, wv = tid >> 6;
  const int l31 = lane & 31, half = lane >> 5;
  const int t0 = c * CHUNK_;

  int rr = rptr[0];
  int centert = c * CHUNK_ + CHUNK_ / 2;
  int expected = (int)((float)centert / (float)rr);
  expected = min(max(expected, 0), S_ - 1);
  int ws0 = min(max(expected - W_ / 2, 0), S_ - W_);

  bf16x8 qf[4];
  {
    const u16* qrow = q_bf + ((size_t)(b * T_ + t0 + wv * 32 + l31)) * D_ + h * 64 + half * 8;
#pragma unroll
    for (int s = 0; s < 4; s++) qf[s] = *(const bf16x8*)(qrow + s * 16);
  }

  const int skey = (tid & 255) >> 3, shq = tid & 7;
  const bool isK = tid < 256;

  auto load_tile = [&](int j) -> uint4 {
    const u16* base;
    size_t row;
    if (j < 2) {
      base = isK ? gk_bf : gv_bf;
      row = (size_t)(b * G_ + j * 32 + skey);
    } else {
      base = isK ? k_bf : v_bf;
      row = (size_t)(b * S_ + ws0 + (j - 2) * 32 + skey);
    }
    return *(const uint4*)(base + row * D_ + h * 64 + shq * 8);
  };

  f32x16 oacc[2];
#pragma unroll
  for (int i = 0; i < 2; i++)
#pragma unroll
    for (int r = 0; r < 16; r++) oacc[i][r] = 0.f;
  float mrun = -1e30f, lsum = 0.f;

  uint4 stg = load_tile(0);

  for (int j = 0; j < NT_; j++) {
    const int bsel = j & 1;
    if (isK) {
      *(uint4*)((char*)smem + bsel * 4096 + ((skey * 128 + shq * 16) ^ ((skey & 7) << 4))) = stg;
    } else {
      const u16* pv = (const u16*)&stg;
      char* bp = (char*)smem + 8192 + bsel * 5248 + shq * 656 + skey * 2;  // 656 = 8*80+16 (row skew)
#pragma unroll
      for (int e = 0; e < 8; e++) *(u16*)(bp + e * 80) = pv[e];
    }
    if (j + 1 < NT_) stg = load_tile(j + 1);
    __syncthreads();

    const int kbase = bsel * 4096;
    const int vtb = 8192 + bsel * 5248;

    f32x16 sacc;
#pragma unroll
    for (int r = 0; r < 16; r++) sacc[r] = 0.f;
    __builtin_amdgcn_s_setprio(1);
#pragma unroll
    for (int s = 0; s < 4; s++) {
      int kbx = kbase + ((l31 * 128 + half * 16 + s * 32) ^ ((l31 & 7) << 4));
      bf16x8 kf = *(const bf16x8*)((char*)smem + kbx);
      sacc = __builtin_amdgcn_mfma_f32_32x32x16_bf16(kf, qf[s], sacc, 0, 0, 0);
    }
    __builtin_amdgcn_s_setprio(0);

    float t0m = fmaxf(fmaxf(sacc[0], sacc[1]), sacc[2]);
    float t1m = fmaxf(fmaxf(sacc[3], sacc[4]), sacc[5]);
    float t2m = fmaxf(fmaxf(sacc[6], sacc[7]), sacc[8]);
    float t3m = fmaxf(fmaxf(sacc[9], sacc[10]), sacc[11]);
    float t4m = fmaxf(fmaxf(sacc[12], sacc[13]), sacc[14]);
    float tmax = fmaxf(fmaxf(fmaxf(t0m, t1m), fmaxf(t2m, t3m)), fmaxf(t4m, sacc[15]));
    tmax = fmaxf(tmax, __shfl_xor(tmax, 32));
    if (__any(tmax > mrun + 8.f)) {
      float mnew = fmaxf(mrun, tmax);
      float fac = __builtin_amdgcn_exp2f(mrun - mnew);
      mrun = mnew;
      lsum *= fac;
#pragma unroll
      for (int i = 0; i < 2; i++)
#pragma unroll
        for (int r = 0; r < 16; r++) oacc[i][r] *= fac;
    }
    float p[16];
#pragma unroll
    for (int r = 0; r < 16; r++) p[r] = __builtin_amdgcn_exp2f(sacc[r] - mrun);
    float s0s = (p[0] + p[1]) + (p[2] + p[3]);
    float s1s = (p[4] + p[5]) + (p[6] + p[7]);
    float s2s = (p[8] + p[9]) + (p[10] + p[11]);
    float s3s = (p[12] + p[13]) + (p[14] + p[15]);
    float tsum = (s0s + s1s) + (s2s + s3s);
    tsum += __shfl_xor(tsum, 32);
    lsum += tsum;

    u32 xs[8], px[8];
#pragma unroll
    for (int i = 0; i < 8; i++)
      asm("v_cvt_pk_bf16_f32 %0, %1, %2" : "=v"(xs[i]) : "v"(p[2 * i]), "v"(p[2 * i + 1]));
#pragma unroll
    for (int i = 0; i < 8; i++) px[i] = (u32)__shfl_xor((int)xs[i], 32);
    u32 Bk[2][4];
    Bk[0][0] = half ? px[2] : xs[0];
    Bk[0][1] = half ? px[3] : xs[1];
    Bk[0][2] = half ? xs[2] : px[0];
    Bk[0][3] = half ? xs[3] : px[1];
    Bk[1][0] = half ? px[6] : xs[4];
    Bk[1][1] = half ? px[7] : xs[5];
    Bk[1][2] = half ? xs[6] : px[4];
    Bk[1][3] = half ? xs[7] : px[5];

    int vro = vtb + l31 * 80 + ((l31 >> 3) << 4) + half * 16;
    __builtin_amdgcn_s_setprio(1);
#pragma unroll
    for (int hdf = 0; hdf < 2; hdf++) {
#pragma unroll
      for (int ks = 0; ks < 2; ks++) {
        bf16x8 vf = *(const bf16x8*)((const char*)smem + vro + hdf * 2624 + ks * 32);  // 2624 = 32*80+64
        uint4 u4;
        u4.x = Bk[ks][0]; u4.y = Bk[ks][1]; u4.z = Bk[ks][2]; u4.w = Bk[ks][3];
        bf16x8 pb = __builtin_bit_cast(bf16x8, u4);
        oacc[hdf] = __builtin_amdgcn_mfma_f32_32x32x16_bf16(vf, pb, oacc[hdf], 0, 0, 0);
      }
    }
    __builtin_amdgcn_s_setprio(0);
  }

  __syncthreads();
  float inv = 1.f / lsum;
#pragma unroll
  for (int hdf = 0; hdf < 2; hdf++) {
#pragma unroll
    for (int a = 0; a < 4; a++) {
      float f0 = oacc[hdf][4 * a] * inv, f1 = oacc[hdf][4 * a + 1] * inv;
      float f2 = oacc[hdf][4 * a + 2] * inv, f3 = oacc[hdf][4 * a + 3] * inv;
      uint2 o;
      asm("v_cvt_pk_bf16_f32 %0, %1, %2" : "=v"(o.x) : "v"(f0), "v"(f1));
      asm("v_cvt_pk_bf16_f32 %0, %1, %2" : "=v"(o.y) : "v"(f2), "v"(f3));
      int off = wv * 4096 + l31 * 128 + ((16 * a + 8 * half + 64 * hdf) ^ ((l31 & 7) << 4));
      *(uint2*)((char*)smem + off) = o;
    }
  }
  __syncthreads();
#pragma unroll
  for (int it = 0; it < 4; it++) {
    int byteo = (tid + it * 512) * 16;
    int row = byteo >> 7;
    int colb = byteo & 127;
    uint4 vv = *(const uint4*)((const char*)smem + row * 128 + (colb ^ ((row & 7) << 4)));
    *(uint4*)(ao + ((size_t)(b * T_ + t0 + row)) * D_ + h * 64 + (colb >> 1)) = vv;
  }
}

extern "C" void kernel_launch(void* const* d_in, const int* in_sizes, int n_in,
                              void* d_out, int out_size, void* d_ws, size_t ws_size,
                              hipStream_t stream) {
  (void)in_sizes; (void)n_in; (void)out_size; (void)ws_size;
  const float* query = (const float*)d_in[0];
  const float* enc = (const float*)d_in[1];
  const float* glob = (const float*)d_in[2];
  const float* qw = (const float*)d_in[3];
  const float* qb = (const float*)d_in[4];
  const float* kw = (const float*)d_in[5];
  const float* kb = (const float*)d_in[6];
  const float* vw = (const float*)d_in[7];
  const float* vb = (const float*)d_in[8];
  const float* gkw = (const float*)d_in[9];
  const float* gkb = (const float*)d_in[10];
  const float* gvw = (const float*)d_in[11];
  const float* gvb = (const float*)d_in[12];
  const float* ow = (const float*)d_in[13];
  const float* ob = (const float*)d_in[14];
  const int* rp = (const int*)d_in[15];

  const size_t NQ = (size_t)B_ * T_ * D_;   // 8388608
  const size_t NG = (size_t)B_ * G_ * D_;   // 131072
  const size_t NW = (size_t)D_ * D_;        // 1048576

  u16* ws = (u16*)d_ws;
  u16* qx = ws;                // bf16 query
  u16* ex = qx + NQ;           // bf16 encoder_out
  u16* gx = ex + NQ;           // bf16 global_tokens
  u16* wgt = gx + NG;          // 6 weights bf16 (qw,kw,vw,gkw,gvw,ow) — contiguous
  u16* q_bf = wgt + 6 * NW;    // projected q (pre-scaled by 0.125*log2e)
  u16* k_bf = q_bf + NQ;
  u16* v_bf = k_bf + NQ;       // contiguous after k_bf (fused K|V)
  u16* gk_bf = v_bf + NQ;
  u16* gv_bf = gk_bf + NG;     // contiguous after gk_bf (fused GK|GV)
  u16* ao = gv_bf + NG;        // attention output bf16 [B*T, D]

  // one fused conversion dispatch: 8192+8192+128+6*1024 = 22656 blocks
  cvt_all_kernel<<<22656, 256, 0, stream>>>(query, enc, glob, qw, kw, vw, gkw, gvw, ow, ws);

  // merged Q + K|V + GK|GV projection: 512 + 256 + 16 = 784 blocks (r5-verified)
  proj_kernel<<<784, 256, 0, stream>>>(ex, qx, gx, wgt, qb, kb, vb, gkb, gvb, q_bf, k_bf, gk_bf);

  attn_kernel<<<dim3(NC_, H_, B_), 512, 0, stream>>>(q_bf, k_bf, v_bf, gk_bf, gv_bf, ao, rp);

  // O projection on the same verified ring structure (separately named for profiling)
  gemmO_kernel<<<256, 256, 0, stream>>>(ao, wgt + 5 * NW, ob, (float*)d_out);
}

// Round 8
// 151.408 us; speedup vs baseline: 1.2128x; 1.0024x over previous
//
#include <hip/hip_runtime.h>

typedef unsigned short u16;
typedef unsigned int u32;
typedef __attribute__((ext_vector_type(4))) float f32x4;
typedef __attribute__((ext_vector_type(16))) float f32x16;
typedef __attribute__((ext_vector_type(8))) short bf16x8;

constexpr int B_ = 2, T_ = 4096, S_ = 4096, G_ = 64, D_ = 1024, H_ = 16, W_ = 512, CHUNK_ = 256;
constexpr int NC_ = T_ / CHUNK_;   // 16 chunks
constexpr int NT_ = (G_ + W_) / 32; // 18 key tiles of 32 (2 global + 16 window)

__device__ __forceinline__ u16 f2bf(float x) {
  u32 u = __builtin_bit_cast(u32, x);
  return (u16)((u + 0x7FFFu + ((u >> 16) & 1u)) >> 16);
}

// ---------------- fused f32 -> bf16 conversion (all 9 segments, one dispatch) ----------------
__global__ __launch_bounds__(256) void cvt_all_kernel(const float* __restrict__ q, const float* __restrict__ e,
                                                      const float* __restrict__ g, const float* __restrict__ w0,
                                                      const float* __restrict__ w1, const float* __restrict__ w2,
                                                      const float* __restrict__ w3, const float* __restrict__ w4,
                                                      const float* __restrict__ w5, u16* __restrict__ dst) {
  int blk = blockIdx.x;
  const float* src;
  int sblk;  // segment start block
  if (blk < 8192) { src = q; sblk = 0; }
  else if (blk < 16384) { src = e; sblk = 8192; }
  else if (blk < 16512) { src = g; sblk = 16384; }
  else if (blk < 17536) { src = w0; sblk = 16512; }
  else if (blk < 18560) { src = w1; sblk = 17536; }
  else if (blk < 19584) { src = w2; sblk = 18560; }
  else if (blk < 20608) { src = w3; sblk = 19584; }
  else if (blk < 21632) { src = w4; sblk = 20608; }
  else { src = w5; sblk = 21632; }
  int li = (blk - sblk) * 256 + threadIdx.x;        // float4 index within segment
  size_t gi = (size_t)blk * 256 + threadIdx.x;      // float4 index within concatenation
  float4 v = ((const float4*)src)[li];
  uint2 o;
  o.x = (u32)f2bf(v.x) | ((u32)f2bf(v.y) << 16);
  o.y = (u32)f2bf(v.z) | ((u32)f2bf(v.w) << 16);
  ((uint2*)dst)[gi] = o;
}

// ---------------- merged projection GEMM: Q + K|V + GK|GV (8-wave ring-3 counted) ----------------
// v8: same 256x128 tile + ring-3 + counted-vmcnt protocol as the twice-verified r5/r7 kernel,
// remapped to 512 threads = 8 waves (4M x 2N, per-wave 64x64 output) -> 4 waves/SIMD at the
// same 72KB LDS / 2 blocks/CU (was 2 waves/SIMD). m114 co-scheduling: more resident waves per
// SIMD cover the staging stalls. Staging per tile: A=2 loads, B=1 load per thread (512 thr x 16B);
// ring-3, stage(t+2) issued inside tile t, boundary wait vmcnt(3) (= stage(t+2)'s 3 newest in
// flight, so stage(t+1) has landed), vmcnt(0) only at the drain tile (t==30). One barrier/tile.
// Routing unchanged: bid<512 K|V; <768 Q (scaled); else GK|GV (M=128, stores guarded).
__global__ __launch_bounds__(512, 2) void proj_kernel(const u16* __restrict__ ex, const u16* __restrict__ qx,
                                                      const u16* __restrict__ gx, const u16* __restrict__ wgt,
                                                      const float* __restrict__ qb, const float* __restrict__ kbias,
                                                      const float* __restrict__ vbias, const float* __restrict__ gkb,
                                                      const float* __restrict__ gvb, u16* __restrict__ q_bf,
                                                      u16* __restrict__ k_bf, u16* __restrict__ gk_bf) {
  __shared__ char lds[73728];  // A ring [0,49152): 3 x 16KB; B ring [49152,73728): 3 x 8KB
  constexpr size_t NW = (size_t)D_ * D_;
  constexpr size_t NQs = (size_t)B_ * T_ * D_;
  constexpr size_t NGs = (size_t)B_ * G_ * D_;
  const int tid = threadIdx.x;
  const int lane = tid & 63;
  const int wid = tid >> 6;
  const int wm = wid >> 1, wn = wid & 1;  // wm 0..3 (64-row slabs), wn 0..1 (64-col slabs)
  const int l15 = lane & 15, kg = lane >> 4;

  const int bid = blockIdx.x;
  const u16 *A, *Bt;
  const float *b1, *b2;
  u16* out;
  int row0, col0, mloc;
  bool scale = false, dual = false;
  size_t dsplit = 0;
  if (bid < 512) {  // K|V: M=8192, N=2048
    row0 = (bid & 31) * 256; col0 = (bid >> 5) * 128; mloc = 256;
    A = ex; Bt = wgt + NW; b1 = kbias; b2 = vbias; out = k_bf; dsplit = NQs; dual = true;
  } else if (bid < 768) {  // Q: M=8192, N=1024
    int i = bid - 512;
    row0 = (i & 31) * 256; col0 = (i >> 5) * 128; mloc = 256;
    A = qx; Bt = wgt; b1 = qb; b2 = qb; out = q_bf; scale = true;
  } else {  // GK|GV: M=128, N=2048 (rows 128..255 read junk in-bounds, stores guarded)
    int i = bid - 768;
    row0 = 0; col0 = i * 128; mloc = 128;
    A = gx; Bt = wgt + 3 * NW; b1 = gkb; b2 = gvb; out = gk_bf; dsplit = NGs; dual = true;
  }
  const float* bp = b1;
  u16* op = out;
  if (dual && col0 >= 1024) { bp = b2 - 1024; op = out + (dsplit - 1024); }

  f32x4 acc[4][4];
#pragma unroll
  for (int i = 0; i < 4; i++)
#pragma unroll
    for (int j = 0; j < 4; j++)
#pragma unroll
      for (int r = 0; r < 4; r++) acc[i][j][r] = 0.f;

  const char* Abase = (const char*)A;
  const char* Bbase = (const char*)Bt;
  // source pre-swizzle: LDS holds chunk (tid&3), logical chunk = (tid&3)^((row>>1)&3);
  // row = p*128 + (tid>>2) -> (row>>1)&3 = (tid>>3)&3 for both p (p*128 contributes 0 mod 4).
  const int swb = 16 * ((tid & 3) ^ ((tid >> 3) & 3));

  auto stageA = [&](int slot, int kt) {
#pragma unroll
    for (int p = 0; p < 2; p++) {
      int dst = slot * 16384 + p * 8192 + tid * 16;
      const char* g = Abase + (size_t)(row0 + p * 128 + (tid >> 2)) * 2048 + kt * 64 + swb;
      __builtin_amdgcn_global_load_lds((const __attribute__((address_space(1))) void*)g,
                                       (__attribute__((address_space(3))) void*)(lds + dst), 16, 0, 0);
    }
  };
  auto stageB = [&](int slot, int kt) {
    int dst = 49152 + slot * 8192 + tid * 16;
    const char* g = Bbase + (size_t)(col0 + (tid >> 2)) * 2048 + kt * 64 + swb;
    __builtin_amdgcn_global_load_lds((const __attribute__((address_space(1))) void*)g,
                                     (__attribute__((address_space(3))) void*)(lds + dst), 16, 0, 0);
  };

  // prologue: stage tiles 0,1 (6 loads/thread); vmcnt(3) -> tile0's 3 landed
  stageA(0, 0); stageB(0, 0);
  stageA(1, 1); stageB(1, 1);
  asm volatile("s_waitcnt vmcnt(3)" ::: "memory");
  __builtin_amdgcn_s_barrier();

  int cur = 0, nx = 2;
  for (int t = 0; t < 32; ++t) {
    const char* Ab = lds + cur * 16384;
    const char* Bb = lds + 49152 + cur * 8192;
    // issue stage(t+2) first (buf[(t+2)%3] readers finished before the prior barrier)
    if (t + 2 < 32) { stageA(nx, t + 2); stageB(nx, t + 2); }
    bf16x8 bq[4], af[4];
#pragma unroll
    for (int ni = 0; ni < 4; ni++) {
      int r = wn * 64 + ni * 16 + l15;
      bq[ni] = *(const bf16x8*)(Bb + ((r * 64 + kg * 16) ^ (((r >> 1) & 3) << 4)));
    }
#pragma unroll
    for (int mi = 0; mi < 4; mi++) {
      int r = wm * 64 + mi * 16 + l15;
      af[mi] = *(const bf16x8*)(Ab + ((r * 64 + kg * 16) ^ (((r >> 1) & 3) << 4)));
    }
    __builtin_amdgcn_s_setprio(1);
#pragma unroll
    for (int mi = 0; mi < 4; mi++)
#pragma unroll
      for (int ni = 0; ni < 4; ni++)
        acc[mi][ni] = __builtin_amdgcn_mfma_f32_16x16x32_bf16(bq[ni], af[mi], acc[mi][ni], 0, 0, 0);
    __builtin_amdgcn_s_setprio(0);
    // boundary: stage(t+1) landed (only stage(t+2)'s 3 may remain in flight)
    if (t < 30) {
      asm volatile("s_waitcnt vmcnt(3)" ::: "memory");
    } else if (t == 30) {
      asm volatile("s_waitcnt vmcnt(0)" ::: "memory");
    }
    __builtin_amdgcn_s_barrier();
    cur = cur == 2 ? 0 : cur + 1;
    nx = nx == 2 ? 0 : nx + 1;
  }

  // epilogue: C[row0+wm*64+mi*16+l15][col0+wn*64+ni*16+kg*4+r], store guarded by mloc
  float4 bv4[4];
#pragma unroll
  for (int ni = 0; ni < 4; ni++) bv4[ni] = *(const float4*)&bp[col0 + wn * 64 + ni * 16 + kg * 4];
#pragma unroll
  for (int mi = 0; mi < 4; mi++) {
    int rloc = wm * 64 + mi * 16 + l15;
    if (rloc >= mloc) continue;  // wave-uniform (mloc=128 cuts wm>=2)
    size_t grow = (size_t)(row0 + rloc);
#pragma unroll
    for (int ni = 0; ni < 4; ni++) {
      int gcol = col0 + wn * 64 + ni * 16 + kg * 4;
      float v0 = acc[mi][ni][0] + bv4[ni].x;
      float v1 = acc[mi][ni][1] + bv4[ni].y;
      float v2 = acc[mi][ni][2] + bv4[ni].z;
      float v3 = acc[mi][ni][3] + bv4[ni].w;
      if (scale) {
        v0 *= 0.18033688011112042f; v1 *= 0.18033688011112042f;  // (1/8)*log2(e)
        v2 *= 0.18033688011112042f; v3 *= 0.18033688011112042f;
      }
      uint2 o;
      asm("v_cvt_pk_bf16_f32 %0, %1, %2" : "=v"(o.x) : "v"(v0), "v"(v1));
      asm("v_cvt_pk_bf16_f32 %0, %1, %2" : "=v"(o.y) : "v"(v2), "v"(v3));
      *(uint2*)&op[grow * 1024 + gcol] = o;
    }
  }
}

// ---------------- O-projection GEMM: same 8-wave ring-3 counted structure, f32 epilogue ----------------
// M=8192, N=1024 -> 256 blocks. 8 waves/block doubles waves/CU vs the 4-wave r7 version.
__global__ __launch_bounds__(512, 2) void gemmO_kernel(const u16* __restrict__ A, const u16* __restrict__ Bt,
                                                       const float* __restrict__ bias, float* __restrict__ out) {
  __shared__ char lds[73728];
  const int tid = threadIdx.x;
  const int lane = tid & 63;
  const int wid = tid >> 6;
  const int wm = wid >> 1, wn = wid & 1;
  const int l15 = lane & 15, kg = lane >> 4;

  const int bid = blockIdx.x;
  const int row0 = (bid & 31) * 256;
  const int col0 = (bid >> 5) * 128;

  f32x4 acc[4][4];
#pragma unroll
  for (int i = 0; i < 4; i++)
#pragma unroll
    for (int j = 0; j < 4; j++)
#pragma unroll
      for (int r = 0; r < 4; r++) acc[i][j][r] = 0.f;

  const char* Abase = (const char*)A;
  const char* Bbase = (const char*)Bt;
  const int swb = 16 * ((tid & 3) ^ ((tid >> 3) & 3));

  auto stageA = [&](int slot, int kt) {
#pragma unroll
    for (int p = 0; p < 2; p++) {
      int dst = slot * 16384 + p * 8192 + tid * 16;
      const char* g = Abase + (size_t)(row0 + p * 128 + (tid >> 2)) * 2048 + kt * 64 + swb;
      __builtin_amdgcn_global_load_lds((const __attribute__((address_space(1))) void*)g,
                                       (__attribute__((address_space(3))) void*)(lds + dst), 16, 0, 0);
    }
  };
  auto stageB = [&](int slot, int kt) {
    int dst = 49152 + slot * 8192 + tid * 16;
    const char* g = Bbase + (size_t)(col0 + (tid >> 2)) * 2048 + kt * 64 + swb;
    __builtin_amdgcn_global_load_lds((const __attribute__((address_space(1))) void*)g,
                                     (__attribute__((address_space(3))) void*)(lds + dst), 16, 0, 0);
  };

  stageA(0, 0); stageB(0, 0);
  stageA(1, 1); stageB(1, 1);
  asm volatile("s_waitcnt vmcnt(3)" ::: "memory");
  __builtin_amdgcn_s_barrier();

  int cur = 0, nx = 2;
  for (int t = 0; t < 32; ++t) {
    const char* Ab = lds + cur * 16384;
    const char* Bb = lds + 49152 + cur * 8192;
    if (t + 2 < 32) { stageA(nx, t + 2); stageB(nx, t + 2); }
    bf16x8 bq[4], af[4];
#pragma unroll
    for (int ni = 0; ni < 4; ni++) {
      int r = wn * 64 + ni * 16 + l15;
      bq[ni] = *(const bf16x8*)(Bb + ((r * 64 + kg * 16) ^ (((r >> 1) & 3) << 4)));
    }
#pragma unroll
    for (int mi = 0; mi < 4; mi++) {
      int r = wm * 64 + mi * 16 + l15;
      af[mi] = *(const bf16x8*)(Ab + ((r * 64 + kg * 16) ^ (((r >> 1) & 3) << 4)));
    }
    __builtin_amdgcn_s_setprio(1);
#pragma unroll
    for (int mi = 0; mi < 4; mi++)
#pragma unroll
      for (int ni = 0; ni < 4; ni++)
        acc[mi][ni] = __builtin_amdgcn_mfma_f32_16x16x32_bf16(bq[ni], af[mi], acc[mi][ni], 0, 0, 0);
    __builtin_amdgcn_s_setprio(0);
    if (t < 30) {
      asm volatile("s_waitcnt vmcnt(3)" ::: "memory");
    } else if (t == 30) {
      asm volatile("s_waitcnt vmcnt(0)" ::: "memory");
    }
    __builtin_amdgcn_s_barrier();
    cur = cur == 2 ? 0 : cur + 1;
    nx = nx == 2 ? 0 : nx + 1;
  }

  float4 bv4[4];
#pragma unroll
  for (int ni = 0; ni < 4; ni++) bv4[ni] = *(const float4*)&bias[col0 + wn * 64 + ni * 16 + kg * 4];
#pragma unroll
  for (int mi = 0; mi < 4; mi++) {
    size_t grow = (size_t)(row0 + wm * 64 + mi * 16 + l15);
#pragma unroll
    for (int ni = 0; ni < 4; ni++) {
      int gcol = col0 + wn * 64 + ni * 16 + kg * 4;
      float4 fo;
      fo.x = acc[mi][ni][0] + bv4[ni].x;
      fo.y = acc[mi][ni][1] + bv4[ni].y;
      fo.z = acc[mi][ni][2] + bv4[ni].z;
      fo.w = acc[mi][ni][3] + bv4[ni].w;
      *(float4*)&out[grow * 1024 + gcol] = fo;
    }
  }
}

// ---------------- fused attention (unchanged, passing) ----------------
__global__ __launch_bounds__(512, 4) void attn_kernel(const u16* __restrict__ q_bf, const u16* __restrict__ k_bf,
                                                      const u16* __restrict__ v_bf, const u16* __restrict__ gk_bf,
                                                      const u16* __restrict__ gv_bf, u16* __restrict__ ao,
                                                      const int* __restrict__ rptr) {
  __shared__ u16 smem[16384];
  const int c = blockIdx.x, h = blockIdx.y, b = blockIdx.z;
  const int tid = threadIdx.x;
  const int lane = tid & 63, wv = tid >> 6;
  const int l31 = lane & 31, half = lane >> 5;
  const int t0 = c * CHUNK_;

  int rr = rptr[0];
  int centert = c * CHUNK_ + CHUNK_ / 2;
  int expected = (int)((float)centert / (float)rr);
  expected = min(max(expected, 0), S_ - 1);
  int ws0 = min(max(expected - W_ / 2, 0), S_ - W_);

  bf16x8 qf[4];
  {
    const u16* qrow = q_bf + ((size_t)(b * T_ + t0 + wv * 32 + l31)) * D_ + h * 64 + half * 8;
#pragma unroll
    for (int s = 0; s < 4; s++) qf[s] = *(const bf16x8*)(qrow + s * 16);
  }

  const int skey = (tid & 255) >> 3, shq = tid & 7;
  const bool isK = tid < 256;

  auto load_tile = [&](int j) -> uint4 {
    const u16* base;
    size_t row;
    if (j < 2) {
      base = isK ? gk_bf : gv_bf;
      row = (size_t)(b * G_ + j * 32 + skey);
    } else {
      base = isK ? k_bf : v_bf;
      row = (size_t)(b * S_ + ws0 + (j - 2) * 32 + skey);
    }
    return *(const uint4*)(base + row * D_ + h * 64 + shq * 8);
  };

  f32x16 oacc[2];
#pragma unroll
  for (int i = 0; i < 2; i++)
#pragma unroll
    for (int r = 0; r < 16; r++) oacc[i][r] = 0.f;
  float mrun = -1e30f, lsum = 0.f;

  uint4 stg = load_tile(0);

  for (int j = 0; j < NT_; j++) {
    const int bsel = j & 1;
    if (isK) {
      *(uint4*)((char*)smem + bsel * 4096 + ((skey * 128 + shq * 16) ^ ((skey & 7) << 4))) = stg;
    } else {
      const u16* pv = (const u16*)&stg;
      char* bp = (char*)smem + 8192 + bsel * 5248 + shq * 656 + skey * 2;  // 656 = 8*80+16 (row skew)
#pragma unroll
      for (int e = 0; e < 8; e++) *(u16*)(bp + e * 80) = pv[e];
    }
    if (j + 1 < NT_) stg = load_tile(j + 1);
    __syncthreads();

    const int kbase = bsel * 4096;
    const int vtb = 8192 + bsel * 5248;

    f32x16 sacc;
#pragma unroll
    for (int r = 0; r < 16; r++) sacc[r] = 0.f;
    __builtin_amdgcn_s_setprio(1);
#pragma unroll
    for (int s = 0; s < 4; s++) {
      int kbx = kbase + ((l31 * 128 + half * 16 + s * 32) ^ ((l31 & 7) << 4));
      bf16x8 kf = *(const bf16x8*)((char*)smem + kbx);
      sacc = __builtin_amdgcn_mfma_f32_32x32x16_bf16(kf, qf[s], sacc, 0, 0, 0);
    }
    __builtin_amdgcn_s_setprio(0);

    float t0m = fmaxf(fmaxf(sacc[0], sacc[1]), sacc[2]);
    float t1m = fmaxf(fmaxf(sacc[3], sacc[4]), sacc[5]);
    float t2m = fmaxf(fmaxf(sacc[6], sacc[7]), sacc[8]);
    float t3m = fmaxf(fmaxf(sacc[9], sacc[10]), sacc[11]);
    float t4m = fmaxf(fmaxf(sacc[12], sacc[13]), sacc[14]);
    float tmax = fmaxf(fmaxf(fmaxf(t0m, t1m), fmaxf(t2m, t3m)), fmaxf(t4m, sacc[15]));
    tmax = fmaxf(tmax, __shfl_xor(tmax, 32));
    if (__any(tmax > mrun + 8.f)) {
      float mnew = fmaxf(mrun, tmax);
      float fac = __builtin_amdgcn_exp2f(mrun - mnew);
      mrun = mnew;
      lsum *= fac;
#pragma unroll
      for (int i = 0; i < 2; i++)
#pragma unroll
        for (int r = 0; r < 16; r++) oacc[i][r] *= fac;
    }
    float p[16];
#pragma unroll
    for (int r = 0; r < 16; r++) p[r] = __builtin_amdgcn_exp2f(sacc[r] - mrun);
    float s0s = (p[0] + p[1]) + (p[2] + p[3]);
    float s1s = (p[4] + p[5]) + (p[6] + p[7]);
    float s2s = (p[8] + p[9]) + (p[10] + p[11]);
    float s3s = (p[12] + p[13]) + (p[14] + p[15]);
    float tsum = (s0s + s1s) + (s2s + s3s);
    tsum += __shfl_xor(tsum, 32);
    lsum += tsum;

    u32 xs[8], px[8];
#pragma unroll
    for (int i = 0; i < 8; i++)
      asm("v_cvt_pk_bf16_f32 %0, %1, %2" : "=v"(xs[i]) : "v"(p[2 * i]), "v"(p[2 * i + 1]));
#pragma unroll
    for (int i = 0; i < 8; i++) px[i] = (u32)__shfl_xor((int)xs[i], 32);
    u32 Bk[2][4];
    Bk[0][0] = half ? px[2] : xs[0];
    Bk[0][1] = half ? px[3] : xs[1];
    Bk[0][2] = half ? xs[2] : px[0];
    Bk[0][3] = half ? xs[3] : px[1];
    Bk[1][0] = half ? px[6] : xs[4];
    Bk[1][1] = half ? px[7] : xs[5];
    Bk[1][2] = half ? xs[6] : px[4];
    Bk[1][3] = half ? xs[7] : px[5];

    int vro = vtb + l31 * 80 + ((l31 >> 3) << 4) + half * 16;
    __builtin_amdgcn_s_setprio(1);
#pragma unroll
    for (int hdf = 0; hdf < 2; hdf++) {
#pragma unroll
      for (int ks = 0; ks < 2; ks++) {
        bf16x8 vf = *(const bf16x8*)((const char*)smem + vro + hdf * 2624 + ks * 32);  // 2624 = 32*80+64
        uint4 u4;
        u4.x = Bk[ks][0]; u4.y = Bk[ks][1]; u4.z = Bk[ks][2]; u4.w = Bk[ks][3];
        bf16x8 pb = __builtin_bit_cast(bf16x8, u4);
        oacc[hdf] = __builtin_amdgcn_mfma_f32_32x32x16_bf16(vf, pb, oacc[hdf], 0, 0, 0);
      }
    }
    __builtin_amdgcn_s_setprio(0);
  }

  __syncthreads();
  float inv = 1.f / lsum;
#pragma unroll
  for (int hdf = 0; hdf < 2; hdf++) {
#pragma unroll
    for (int a = 0; a < 4; a++) {
      float f0 = oacc[hdf][4 * a] * inv, f1 = oacc[hdf][4 * a + 1] * inv;
      float f2 = oacc[hdf][4 * a + 2] * inv, f3 = oacc[hdf][4 * a + 3] * inv;
      uint2 o;
      asm("v_cvt_pk_bf16_f32 %0, %1, %2" : "=v"(o.x) : "v"(f0), "v"(f1));
      asm("v_cvt_pk_bf16_f32 %0, %1, %2" : "=v"(o.y) : "v"(f2), "v"(f3));
      int off = wv * 4096 + l31 * 128 + ((16 * a + 8 * half + 64 * hdf) ^ ((l31 & 7) << 4));
      *(uint2*)((char*)smem + off) = o;
    }
  }
  __syncthreads();
#pragma unroll
  for (int it = 0; it < 4; it++) {
    int byteo = (tid + it * 512) * 16;
    int row = byteo >> 7;
    int colb = byteo & 127;
    uint4 vv = *(const uint4*)((const char*)smem + row * 128 + (colb ^ ((row & 7) << 4)));
    *(uint4*)(ao + ((size_t)(b * T_ + t0 + row)) * D_ + h * 64 + (colb >> 1)) = vv;
  }
}

extern "C" void kernel_launch(void* const* d_in, const int* in_sizes, int n_in,
                              void* d_out, int out_size, void* d_ws, size_t ws_size,
                              hipStream_t stream) {
  (void)in_sizes; (void)n_in; (void)out_size; (void)ws_size;
  const float* query = (const float*)d_in[0];
  const float* enc = (const float*)d_in[1];
  const float* glob = (const float*)d_in[2];
  const float* qw = (const float*)d_in[3];
  const float* qb = (const float*)d_in[4];
  const float* kw = (const float*)d_in[5];
  const float* kb = (const float*)d_in[6];
  const float* vw = (const float*)d_in[7];
  const float* vb = (const float*)d_in[8];
  const float* gkw = (const float*)d_in[9];
  const float* gkb = (const float*)d_in[10];
  const float* gvw = (const float*)d_in[11];
  const float* gvb = (const float*)d_in[12];
  const float* ow = (const float*)d_in[13];
  const float* ob = (const float*)d_in[14];
  const int* rp = (const int*)d_in[15];

  const size_t NQ = (size_t)B_ * T_ * D_;   // 8388608
  const size_t NG = (size_t)B_ * G_ * D_;   // 131072
  const size_t NW = (size_t)D_ * D_;        // 1048576

  u16* ws = (u16*)d_ws;
  u16* qx = ws;                // bf16 query
  u16* ex = qx + NQ;           // bf16 encoder_out
  u16* gx = ex + NQ;           // bf16 global_tokens
  u16* wgt = gx + NG;          // 6 weights bf16 (qw,kw,vw,gkw,gvw,ow) — contiguous
  u16* q_bf = wgt + 6 * NW;    // projected q (pre-scaled by 0.125*log2e)
  u16* k_bf = q_bf + NQ;
  u16* v_bf = k_bf + NQ;       // contiguous after k_bf (fused K|V)
  u16* gk_bf = v_bf + NQ;
  u16* gv_bf = gk_bf + NG;     // contiguous after gk_bf (fused GK|GV)
  u16* ao = gv_bf + NG;        // attention output bf16 [B*T, D]

  // one fused conversion dispatch: 8192+8192+128+6*1024 = 22656 blocks
  cvt_all_kernel<<<22656, 256, 0, stream>>>(query, enc, glob, qw, kw, vw, gkw, gvw, ow, ws);

  // merged Q + K|V + GK|GV projection: 784 blocks, 8 waves each (2 blocks/CU, 4 waves/SIMD)
  proj_kernel<<<784, 512, 0, stream>>>(ex, qx, gx, wgt, qb, kb, vb, gkb, gvb, q_bf, k_bf, gk_bf);

  attn_kernel<<<dim3(NC_, H_, B_), 512, 0, stream>>>(q_bf, k_bf, v_bf, gk_bf, gv_bf, ao, rp);

  // O projection, 8-wave ring structure
  gemmO_kernel<<<256, 512, 0, stream>>>(ao, wgt + 5 * NW, ob, (float*)d_out);
}